// Round 4
// baseline (729.124 us; speedup 1.0000x reference)
//
#include <hip/hip_runtime.h>
#include <cstdio>
#include <cstdint>

// RGCN block, fused aggregation+GEMM:
//   per 128-dst block, for r in 0..8:  (r==8 is the root/identity "relation")
//     gather mean_r(x[src]) for the block's dsts into a swizzled LDS tile (bf16),
//     MFMA tile @ W_r (W read direct from L2-resident wbfT), accumulate in VGPRs.
//   Epilogue: h = acc + bias -> d_out, column sums/sumsq via shfl+atomics.
//   Then k_final: BN(batch stats) + PReLU + residual.
// CSR grouped by (dst, rel) via counting sort; edge records are u16 src.
// NOTE: harness delivers integer inputs as int32 (edge_index int64 -> const int*).

constexpr int kN  = 50000;   // nodes
constexpr int kE  = 800000;  // edges
constexpr int kR  = 8;       // relations
constexpr int kC  = 256;     // channels
constexpr int kK  = 2304;    // 9*256 (wbfT k-extent: 8 rels + root)
constexpr int kNB = 391;     // ceil(kN/128)

typedef __attribute__((ext_vector_type(8))) short bf16x8;
typedef __attribute__((ext_vector_type(4))) float f32x4;
typedef __attribute__((ext_vector_type(2))) unsigned int u32x2;

__device__ __forceinline__ unsigned short f2bf(float f) {
  unsigned u = __builtin_bit_cast(unsigned, f);
  u = u + 0x7FFFu + ((u >> 16) & 1u);
  return (unsigned short)(u >> 16);
}
__device__ __forceinline__ float bf2f(unsigned short s) {
  unsigned u = ((unsigned)s) << 16;
  return __builtin_bit_cast(float, u);
}

// ---- per-edge counts: cnt[rel*N+dst], deg[dst] ----
__global__ void k_count(const int* __restrict__ ei, const float* __restrict__ ea,
                        int* __restrict__ cnt, int* __restrict__ deg) {
  int e = blockIdx.x * blockDim.x + threadIdx.x;
  if (e >= kE) return;
  int dst = ei[kE + e];
  int rel = (int)ea[(size_t)e * 5 + 4];
  if ((unsigned)dst >= (unsigned)kN || (unsigned)rel >= (unsigned)kR) return;
  atomicAdd(&cnt[rel * kN + dst], 1);
  atomicAdd(&deg[dst], 1);
}

// ---- convert x -> contiguous bf16 ----
__global__ void k_convert_x(const float* __restrict__ x, unsigned short* __restrict__ xbf) {
  int i = (blockIdx.x * blockDim.x + threadIdx.x) * 4;
  if (i >= kN * kC) return;
  float4 v = *(const float4*)(x + i);
  ushort4 o;
  o.x = f2bf(v.x); o.y = f2bf(v.y); o.z = f2bf(v.z); o.w = f2bf(v.w);
  *(ushort4*)(xbf + i) = o;
}

// ---- convert W+root -> bf16 transposed: wbfT[c][k], k<2048: W[k>>8][k&255][c]; else root[k-2048][c] ----
__global__ void k_convert_w(const float* __restrict__ W, const float* __restrict__ root,
                            unsigned short* __restrict__ wbfT) {
  int t = blockIdx.x * blockDim.x + threadIdx.x;   // c*kK + k
  if (t >= kC * kK) return;
  int c = t / kK, k = t - c * kK;
  float v;
  if (k < kR * kC) {
    int r = k >> 8, kk = k & 255;
    v = W[(size_t)r * kC * kC + (size_t)kk * kC + c];
  } else {
    v = root[(size_t)(k - kR * kC) * kC + c];
  }
  wbfT[(size_t)c * kK + k] = f2bf(v);
}

// ---- exclusive scan of deg -> off ----
__global__ __launch_bounds__(1024) void k_scan(const int* __restrict__ deg, int* __restrict__ off) {
  __shared__ int wsum[16];
  int t = threadIdx.x;
  const int slab = (kN + 1023) / 1024;   // 49
  int lo = t * slab, hi = min(lo + slab, kN);
  int s = 0;
  for (int i = lo; i < hi; ++i) s += deg[i];
  int incl = s;
#pragma unroll
  for (int d = 1; d < 64; d <<= 1) {
    int v = __shfl_up(incl, d);
    if ((t & 63) >= d) incl += v;
  }
  if ((t & 63) == 63) wsum[t >> 6] = incl;
  __syncthreads();
  if (t == 0) {
    int run = 0;
#pragma unroll
    for (int i = 0; i < 16; ++i) { int tmp = wsum[i]; wsum[i] = run; run += tmp; }
  }
  __syncthreads();
  int base = wsum[t >> 6] + incl - s;
  for (int i = lo; i < hi; ++i) { off[i] = base; base += deg[i]; }
  if (t == 1023) off[kN] = base;
}

// ---- per-(rel,dst) group cursors: cur[r*N+dst] = off[dst] + prefix_r(cnt) ----
__global__ void k_grp(const int* __restrict__ off, const int* __restrict__ cnt,
                      int* __restrict__ cur) {
  int t = blockIdx.x * blockDim.x + threadIdx.x;
  if (t >= kN) return;
  int o = off[t];
#pragma unroll
  for (int r = 0; r < kR; ++r) { cur[r * kN + t] = o; o += cnt[r * kN + t]; }
}

// ---- fill CSR edge records (u16 src), grouped (dst, rel); cur becomes group ENDs ----
__global__ void k_fill(const int* __restrict__ ei, const float* __restrict__ ea,
                       int* __restrict__ cur, unsigned short* __restrict__ ebuf) {
  int e = blockIdx.x * blockDim.x + threadIdx.x;
  if (e >= kE) return;
  int src = ei[e];
  int dst = ei[kE + e];
  int rel = (int)ea[(size_t)e * 5 + 4];
  if ((unsigned)dst >= (unsigned)kN || (unsigned)rel >= (unsigned)kR) return;
  int pos = atomicAdd(&cur[rel * kN + dst], 1);
  ebuf[pos] = (unsigned short)src;
}

// ---- fused gather + GEMM + stats ----
// 391 blocks x 256 threads; block = 128 dst rows x 256 out cols.
// LDS: Ms[128][256] bf16, XOR-swizzled (byte ^= (row&7)<<4 on bits 4-6).
__global__ __launch_bounds__(256, 2) void k_fused(const unsigned short* __restrict__ xbf,
                                                  const unsigned short* __restrict__ wbfT,
                                                  const unsigned short* __restrict__ ebuf,
                                                  const int* __restrict__ off,
                                                  const int* __restrict__ cur,
                                                  const float* __restrict__ bias,
                                                  float* __restrict__ out,
                                                  float* __restrict__ cs,
                                                  float* __restrict__ csq) {
  __shared__ __align__(16) unsigned short Ms[128 * 256];  // 64 KB
  const int tid = threadIdx.x;
  const int lane = tid & 63, wv = tid >> 6;
  const int d0 = blockIdx.x * 128;
  const int wm = wv >> 1, wn = wv & 1;   // 2x2 wave grid: 64 rows x 128 cols each
  f32x4 acc[4][8] = {};

  // preload group boundaries: lane<32 holds dst = d0 + wv*32 + lane
  int bnd[9];
  {
    int dl = d0 + wv * 32 + lane;
    bool ok = (lane < 32) && (dl < kN);
    bnd[0] = ok ? off[dl] : 0;
#pragma unroll
    for (int r = 0; r < kR; ++r) bnd[r + 1] = ok ? cur[r * kN + dl] : 0;
  }

  for (int r = 0; r < 9; ++r) {
    // ---- gather: this wave fills Ms rows wv*32 .. wv*32+31 ----
    for (int d = 0; d < 32; ++d) {
      const int lr = wv * 32 + d;
      float s0 = 0.f, s1 = 0.f, s2 = 0.f, s3 = 0.f;
      float sc;
      if (r < kR) {
        int st = __shfl(bnd[r], d);
        int en = __shfl(bnd[r + 1], d);
        for (int e = st; e < en; ++e) {
          int src = ebuf[e];   // wave-uniform broadcast load
          ushort4 v = *(const ushort4*)(xbf + (size_t)src * kC + lane * 4);
          s0 += bf2f(v.x); s1 += bf2f(v.y); s2 += bf2f(v.z); s3 += bf2f(v.w);
        }
        int c = en - st;
        sc = c > 0 ? 1.f / (float)c : 0.f;
      } else {                 // root: identity row
        int dst = d0 + lr;
        if (dst < kN) {
          ushort4 v = *(const ushort4*)(xbf + (size_t)dst * kC + lane * 4);
          s0 = bf2f(v.x); s1 = bf2f(v.y); s2 = bf2f(v.z); s3 = bf2f(v.w);
        }
        sc = 1.f;
      }
      unsigned lo = (unsigned)f2bf(s0 * sc) | ((unsigned)f2bf(s1 * sc) << 16);
      unsigned hi = (unsigned)f2bf(s2 * sc) | ((unsigned)f2bf(s3 * sc) << 16);
      unsigned byte = (unsigned)(lane * 8) ^ (unsigned)((lr & 7) << 4);  // swizzled write
      *(u32x2*)((char*)Ms + lr * 512 + byte) = u32x2{lo, hi};
    }
    __syncthreads();

    // ---- MFMA: acc += Ms @ W_r ----
    const int rbase = r * 256;
    const int ksh_l = (lane >> 4) * 8;
#pragma unroll
    for (int kc = 0; kc < 8; ++kc) {
      const int ksh = kc * 32 + ksh_l;
      bf16x8 a[4], b[8];
#pragma unroll
      for (int i = 0; i < 4; ++i) {
        int row = wm * 64 + i * 16 + (lane & 15);
        unsigned byte = (unsigned)(ksh * 2) ^ (unsigned)((row & 7) << 4);  // swizzled read
        a[i] = *(const bf16x8*)((const char*)Ms + row * 512 + byte);
      }
#pragma unroll
      for (int j = 0; j < 8; ++j) {
        int col = wn * 128 + j * 16 + (lane & 15);
        b[j] = *(const bf16x8*)(wbfT + (size_t)col * kK + rbase + ksh);   // L2-hot
      }
#pragma unroll
      for (int i = 0; i < 4; ++i)
#pragma unroll
        for (int j = 0; j < 8; ++j)
          acc[i][j] = __builtin_amdgcn_mfma_f32_16x16x32_bf16(a[i], b[j], acc[i][j], 0, 0, 0);
    }
    __syncthreads();
  }

  // ---- epilogue: store h = acc + bias; column stats on raw acc ----
#pragma unroll
  for (int j = 0; j < 8; ++j) {
    int col = wn * 128 + j * 16 + (lane & 15);
    float bv = bias[col];
    float s = 0.f, ss = 0.f;
#pragma unroll
    for (int i = 0; i < 4; ++i) {
      int rb = d0 + wm * 64 + i * 16 + (lane >> 4) * 4;
#pragma unroll
      for (int q = 0; q < 4; ++q) {
        float v = acc[i][j][q];
        s += v; ss += v * v;
        int row = rb + q;
        if (row < kN) out[(size_t)row * kC + col] = v + bv;
      }
    }
    s  += __shfl_xor(s, 16);  s  += __shfl_xor(s, 32);
    ss += __shfl_xor(ss, 16); ss += __shfl_xor(ss, 32);
    if (lane < 16) { atomicAdd(&cs[col], s); atomicAdd(&csq[col], ss); }
  }
}

// ---- BN normalize + PReLU + residual (stats are bias-free; shift mu by bias) ----
__global__ void k_final(float* __restrict__ h, const float* __restrict__ x,
                        const float* __restrict__ cs, const float* __restrict__ csq,
                        const float* __restrict__ bias,
                        const float* __restrict__ gamma, const float* __restrict__ beta,
                        const float* __restrict__ prelu) {
  int idx = (blockIdx.x * blockDim.x + threadIdx.x) * 4;
  if (idx >= kN * kC) return;
  int col = idx & 255;
  const float inv_n = 1.0f / (float)kN;
  float a = prelu[0];
  float4 hv = *(float4*)(h + idx);
  float4 xv = *(const float4*)(x + idx);
  float hr[4] = {hv.x, hv.y, hv.z, hv.w};
  float xr[4] = {xv.x, xv.y, xv.z, xv.w};
#pragma unroll
  for (int j = 0; j < 4; ++j) {
    int c = col + j;
    float mu_raw = cs[c] * inv_n;
    float var = csq[c] * inv_n - mu_raw * mu_raw;
    float mu  = mu_raw + bias[c];          // h was stored with bias added
    float k   = gamma[c] * rsqrtf(var + 1e-5f);
    float v   = (hr[j] - mu) * k + beta[c];
    v = v > 0.f ? v : a * v;
    hr[j] = v + xr[j];
  }
  *(float4*)(h + idx) = make_float4(hr[0], hr[1], hr[2], hr[3]);
}

extern "C" void kernel_launch(void* const* d_in, const int* in_sizes, int n_in,
                              void* d_out, int out_size, void* d_ws, size_t ws_size,
                              hipStream_t stream) {
  const float* x     = (const float*)d_in[0];
  const int*   ei    = (const int*)d_in[1];     // int64 in ref -> int32 from harness
  const float* ea    = (const float*)d_in[2];
  const float* W     = (const float*)d_in[3];
  const float* root  = (const float*)d_in[4];
  const float* bias  = (const float*)d_in[5];
  const float* gamma = (const float*)d_in[6];
  const float* beta  = (const float*)d_in[7];
  const float* prelu = (const float*)d_in[8];
  float* out = (float*)d_out;
  char* ws = (char*)d_ws;

  size_t o = 0;
  auto alloc = [&](size_t sz) { size_t r = o; o += (sz + 255) & ~(size_t)255; return r; };
  size_t xbf_o = alloc((size_t)kN * kC * 2);        // 25.6 MB
  size_t wbf_o = alloc((size_t)kC * kK * 2);        // 1.2 MB
  size_t cnt_o = alloc((size_t)kR * kN * 4);        // 1.6 MB
  size_t deg_o = alloc((size_t)kN * 4);
  size_t cs_o  = alloc(256 * 4);
  size_t csq_o = alloc(256 * 4);
  size_t zend  = o;                                 // end of must-zero region
  size_t off_o = alloc((size_t)(kN + 1) * 4);
  size_t cur_o = alloc((size_t)kR * kN * 4);
  size_t eb_o  = alloc((size_t)kE * 2);             // u16 src records
  if (o > ws_size) {
    fprintf(stderr, "[RGCN kernel] ws too small: need %zu have %zu\n", o, ws_size);
    return;
  }

  unsigned short* xbf  = (unsigned short*)(ws + xbf_o);
  unsigned short* wbfT = (unsigned short*)(ws + wbf_o);
  int*   cnt  = (int*)(ws + cnt_o);
  int*   deg  = (int*)(ws + deg_o);
  float* cs   = (float*)(ws + cs_o);
  float* csq  = (float*)(ws + csq_o);
  int*   offp = (int*)(ws + off_o);
  int*   cur  = (int*)(ws + cur_o);
  unsigned short* ebuf = (unsigned short*)(ws + eb_o);

  hipMemsetAsync(ws + cnt_o, 0, zend - cnt_o, stream);           // cnt/deg/cs/csq
  k_count<<<(kE + 255) / 256, 256, 0, stream>>>(ei, ea, cnt, deg);
  k_convert_x<<<(kN * kC / 4) / 256, 256, 0, stream>>>(x, xbf);
  k_convert_w<<<(kC * kK + 255) / 256, 256, 0, stream>>>(W, root, wbfT);
  k_scan<<<1, 1024, 0, stream>>>(deg, offp);
  k_grp<<<(kN + 255) / 256, 256, 0, stream>>>(offp, cnt, cur);
  k_fill<<<(kE + 255) / 256, 256, 0, stream>>>(ei, ea, cur, ebuf);
  k_fused<<<kNB, 256, 0, stream>>>(xbf, wbfT, ebuf, offp, cur, bias, out, cs, csq);
  k_final<<<(kN * kC / 4) / 256, 256, 0, stream>>>(out, x, cs, csq, bias, gamma, beta, prelu);
}

// Round 5
// 483.674 us; speedup vs baseline: 1.5075x; 1.5075x over previous
//
#include <hip/hip_runtime.h>
#include <cstdio>
#include <cstdint>

// RGCN block, aggregation-first (round-3 structure + swizzled GEMM LDS + fused BN stats):
//   M[dst, r*256+ch] = mean_{edges (src->dst, rel=r)} x_bf16[src, ch]
//   A = [M | x_bf16]  (50048 x 2304),  B = [W_0..W_7 ; root]  (2304 x 256)
//   h = A @ B + bias  -> BN(batch stats) -> PReLU -> + x
// CSR grouped by (dst, rel) via counting sort; edge records are u16 src.
// NOTE: harness delivers integer inputs as int32 (edge_index int64 -> const int*).

constexpr int kN  = 50000;   // nodes
constexpr int kE  = 800000;  // edges
constexpr int kR  = 8;       // relations
constexpr int kC  = 256;     // channels
constexpr int kMP = 50048;   // padded rows (391*128)
constexpr int kK  = 2304;    // GEMM K = 8*256 + 256

typedef __attribute__((ext_vector_type(8))) short bf16x8;
typedef __attribute__((ext_vector_type(4))) float f32x4;
typedef __attribute__((ext_vector_type(2))) unsigned int u32x2;

__device__ __forceinline__ unsigned short f2bf(float f) {
  unsigned u = __builtin_bit_cast(unsigned, f);
  u = u + 0x7FFFu + ((u >> 16) & 1u);
  return (unsigned short)(u >> 16);
}
__device__ __forceinline__ float bf2f(unsigned short s) {
  unsigned u = ((unsigned)s) << 16;
  return __builtin_bit_cast(float, u);
}
__device__ __forceinline__ void gload16(const void* g, void* l) {
  __builtin_amdgcn_global_load_lds((__attribute__((address_space(1))) const void*)g,
                                   (__attribute__((address_space(3))) void*)l, 16, 0, 0);
}

// ---- per-edge counts: cnt[rel*N+dst], deg[dst] ----
__global__ void k_count(const int* __restrict__ ei, const float* __restrict__ ea,
                        int* __restrict__ cnt, int* __restrict__ deg) {
  int e = blockIdx.x * blockDim.x + threadIdx.x;
  if (e >= kE) return;
  int dst = ei[kE + e];
  int rel = (int)ea[(size_t)e * 5 + 4];
  if ((unsigned)dst >= (unsigned)kN || (unsigned)rel >= (unsigned)kR) return;
  atomicAdd(&cnt[rel * kN + dst], 1);
  atomicAdd(&deg[dst], 1);
}

// ---- convert x -> bf16 into A cols 2048..2303 ----
__global__ void k_convert_x(const float* __restrict__ x, unsigned short* __restrict__ A) {
  int i = (blockIdx.x * blockDim.x + threadIdx.x) * 4;
  if (i >= kN * kC) return;
  int row = i >> 8, col = i & 255;
  float4 v = *(const float4*)(x + i);
  ushort4 o;
  o.x = f2bf(v.x); o.y = f2bf(v.y); o.z = f2bf(v.z); o.w = f2bf(v.w);
  *(ushort4*)(A + (size_t)row * kK + 2048 + col) = o;
}

// ---- convert W+root -> bf16 transposed: wbfT[c][k], k<2048: W[k>>8][k&255][c]; else root[k-2048][c] ----
__global__ void k_convert_w(const float* __restrict__ W, const float* __restrict__ root,
                            unsigned short* __restrict__ wbfT) {
  int t = blockIdx.x * blockDim.x + threadIdx.x;   // c*kK + k
  if (t >= kC * kK) return;
  int c = t / kK, k = t - c * kK;
  float v;
  if (k < kR * kC) {
    int r = k >> 8, kk = k & 255;
    v = W[(size_t)r * kC * kC + (size_t)kk * kC + c];
  } else {
    v = root[(size_t)(k - kR * kC) * kC + c];
  }
  wbfT[(size_t)c * kK + k] = f2bf(v);
}

// ---- exclusive scan of deg -> off ----
__global__ __launch_bounds__(1024) void k_scan(const int* __restrict__ deg, int* __restrict__ off) {
  __shared__ int wsum[16];
  int t = threadIdx.x;
  const int slab = (kN + 1023) / 1024;   // 49
  int lo = t * slab, hi = min(lo + slab, kN);
  int s = 0;
  for (int i = lo; i < hi; ++i) s += deg[i];
  int incl = s;
#pragma unroll
  for (int d = 1; d < 64; d <<= 1) {
    int v = __shfl_up(incl, d);
    if ((t & 63) >= d) incl += v;
  }
  if ((t & 63) == 63) wsum[t >> 6] = incl;
  __syncthreads();
  if (t == 0) {
    int run = 0;
#pragma unroll
    for (int i = 0; i < 16; ++i) { int tmp = wsum[i]; wsum[i] = run; run += tmp; }
  }
  __syncthreads();
  int base = wsum[t >> 6] + incl - s;
  for (int i = lo; i < hi; ++i) { off[i] = base; base += deg[i]; }
  if (t == 1023) off[kN] = base;
}

// ---- per-(rel,dst) group cursors ----
__global__ void k_grp(const int* __restrict__ off, const int* __restrict__ cnt,
                      int* __restrict__ cur) {
  int t = blockIdx.x * blockDim.x + threadIdx.x;
  if (t >= kN) return;
  int o = off[t];
#pragma unroll
  for (int r = 0; r < kR; ++r) { cur[r * kN + t] = o; o += cnt[r * kN + t]; }
}

// ---- fill CSR edge records (u16 src), grouped (dst, rel) ----
__global__ void k_fill(const int* __restrict__ ei, const float* __restrict__ ea,
                       int* __restrict__ cur, unsigned short* __restrict__ ebuf) {
  int e = blockIdx.x * blockDim.x + threadIdx.x;
  if (e >= kE) return;
  int src = ei[e];
  int dst = ei[kE + e];
  int rel = (int)ea[(size_t)e * 5 + 4];
  if ((unsigned)dst >= (unsigned)kN || (unsigned)rel >= (unsigned)kR) return;
  int pos = atomicAdd(&cur[rel * kN + dst], 1);
  ebuf[pos] = (unsigned short)src;
}

// ---- aggregation: 1 wave per dst; mean x[src] per relation -> A cols 0..2047 (nontemporal) ----
__global__ __launch_bounds__(256) void k_agg(const unsigned short* __restrict__ ebuf,
                                             const int* __restrict__ off,
                                             const int* __restrict__ cnt,
                                             unsigned short* A) {
  int dst = blockIdx.x * 4 + (threadIdx.x >> 6);
  if (dst >= kN) return;
  int lane = threadIdx.x & 63;
  int e = off[dst];
  const unsigned short* xcols = A + 2048 + lane * 4;   // x region of A
  unsigned short* mrow = A + (size_t)dst * kK + lane * 4;
#pragma unroll
  for (int r = 0; r < kR; ++r) {
    int c = cnt[r * kN + dst];
    float s0 = 0.f, s1 = 0.f, s2 = 0.f, s3 = 0.f;
    for (int k = 0; k < c; ++k) {
      int src = ebuf[e + k];
      ushort4 v = *(const ushort4*)(xcols + (size_t)src * kK);
      s0 += bf2f(v.x); s1 += bf2f(v.y); s2 += bf2f(v.z); s3 += bf2f(v.w);
    }
    e += c;
    float sc = c > 0 ? 1.f / (float)c : 0.f;
    unsigned lo = (unsigned)f2bf(s0 * sc) | ((unsigned)f2bf(s1 * sc) << 16);
    unsigned hi = (unsigned)f2bf(s2 * sc) | ((unsigned)f2bf(s3 * sc) << 16);
    u32x2 pk = {lo, hi};
    __builtin_nontemporal_store(pk, (u32x2*)(mrow + r * 256));   // don't evict x from L3
  }
}

// ---- GEMM [kMP x 2304] @ [2304 x 256] -> d_out f32 (+bias), fused BN column stats ----
// LDS tiles XOR-swizzled: content at byte (row*128 + b) holds k-chunk (b ^ ((row&7)<<4)).
// Write side stays linear (global_load_lds); the per-lane GLOBAL chunk is pre-swizzled,
// valid because row&7 == lane>>3 in this staging pattern (rule #21 / m173).
__global__ __launch_bounds__(256) void k_gemm(const unsigned short* __restrict__ A,
                                              const unsigned short* __restrict__ wbfT,
                                              float* __restrict__ out,
                                              const float* __restrict__ bias,
                                              float* __restrict__ cs,
                                              float* __restrict__ csq) {
  __shared__ __align__(16) unsigned short As[128 * 64];  // [row][k], swizzled content
  __shared__ __align__(16) unsigned short Bs[128 * 64];  // [col][k], swizzled content
  const int tid = threadIdx.x;
  const int lane = tid & 63, wv = tid >> 6;
  const int n0 = blockIdx.x * 128, m0 = blockIdx.y * 128;
  const int wm = wv >> 1, wn = wv & 1;  // 2x2 wave grid, 64x64 out each
  f32x4 acc[4][4] = {};

  const int srow = (lane >> 3);                         // 0..7 == row&7
  const int skk  = ((lane & 7) ^ srow) * 8;             // pre-swizzled global k-chunk
  for (int kt = 0; kt < kK / 64; ++kt) {
    const int kb = kt * 64;
#pragma unroll
    for (int c = 0; c < 4; ++c) {
      int row = c * 32 + wv * 8 + srow;
      gload16(A    + (size_t)(m0 + row) * kK + kb + skk, &As[c * 2048 + wv * 512]);
      gload16(wbfT + (size_t)(n0 + row) * kK + kb + skk, &Bs[c * 2048 + wv * 512]);
    }
    __syncthreads();
#pragma unroll
    for (int kk = 0; kk < 64; kk += 32) {
      const int koff = kk + (lane >> 4) * 8;
      bf16x8 a[4], b[4];
#pragma unroll
      for (int i = 0; i < 4; ++i) {
        int ra = wm * 64 + i * 16 + (lane & 15);
        int rb = wn * 64 + i * 16 + (lane & 15);
        unsigned ba = (unsigned)(koff * 2) ^ (unsigned)((ra & 7) << 4);
        unsigned bb = (unsigned)(koff * 2) ^ (unsigned)((rb & 7) << 4);
        a[i] = *(const bf16x8*)((const char*)As + ra * 128 + ba);
        b[i] = *(const bf16x8*)((const char*)Bs + rb * 128 + bb);
      }
#pragma unroll
      for (int i = 0; i < 4; ++i)
#pragma unroll
        for (int j = 0; j < 4; ++j)
          acc[i][j] = __builtin_amdgcn_mfma_f32_16x16x32_bf16(a[i], b[j], acc[i][j], 0, 0, 0);
    }
    __syncthreads();
  }

  // C/D layout: col = lane&15, row = (lane>>4)*4 + r.  Stats on raw acc (bias-free;
  // pad rows have zero acc so they contribute nothing to the sums).
#pragma unroll
  for (int j = 0; j < 4; ++j) {
    int col = n0 + wn * 64 + j * 16 + (lane & 15);
    float bv = bias[col];
    float s = 0.f, ss = 0.f;
#pragma unroll
    for (int i = 0; i < 4; ++i) {
      int rb = m0 + wm * 64 + i * 16 + (lane >> 4) * 4;
#pragma unroll
      for (int q = 0; q < 4; ++q) {
        float v = acc[i][j][q];
        s += v; ss += v * v;
        int row = rb + q;
        if (row < kN) out[(size_t)row * kC + col] = v + bv;
      }
    }
    s  += __shfl_xor(s, 16);  s  += __shfl_xor(s, 32);
    ss += __shfl_xor(ss, 16); ss += __shfl_xor(ss, 32);
    if (lane < 16) { atomicAdd(&cs[col], s); atomicAdd(&csq[col], ss); }
  }
}

// ---- BN normalize + PReLU + residual (stats are bias-free; shift mu by bias) ----
__global__ void k_final(float* __restrict__ h, const float* __restrict__ x,
                        const float* __restrict__ cs, const float* __restrict__ csq,
                        const float* __restrict__ bias,
                        const float* __restrict__ gamma, const float* __restrict__ beta,
                        const float* __restrict__ prelu) {
  int idx = (blockIdx.x * blockDim.x + threadIdx.x) * 4;
  if (idx >= kN * kC) return;
  int col = idx & 255;
  const float inv_n = 1.0f / (float)kN;
  float a = prelu[0];
  float4 hv = *(float4*)(h + idx);
  float4 xv = *(const float4*)(x + idx);
  float hr[4] = {hv.x, hv.y, hv.z, hv.w};
  float xr[4] = {xv.x, xv.y, xv.z, xv.w};
#pragma unroll
  for (int j = 0; j < 4; ++j) {
    int c = col + j;
    float mu_raw = cs[c] * inv_n;
    float var = csq[c] * inv_n - mu_raw * mu_raw;
    float mu  = mu_raw + bias[c];          // h was stored with bias added
    float k   = gamma[c] * rsqrtf(var + 1e-5f);
    float v   = (hr[j] - mu) * k + beta[c];
    v = v > 0.f ? v : a * v;
    hr[j] = v + xr[j];
  }
  *(float4*)(h + idx) = make_float4(hr[0], hr[1], hr[2], hr[3]);
}

extern "C" void kernel_launch(void* const* d_in, const int* in_sizes, int n_in,
                              void* d_out, int out_size, void* d_ws, size_t ws_size,
                              hipStream_t stream) {
  const float* x     = (const float*)d_in[0];
  const int*   ei    = (const int*)d_in[1];     // int64 in ref -> int32 from harness
  const float* ea    = (const float*)d_in[2];
  const float* W     = (const float*)d_in[3];
  const float* root  = (const float*)d_in[4];
  const float* bias  = (const float*)d_in[5];
  const float* gamma = (const float*)d_in[6];
  const float* beta  = (const float*)d_in[7];
  const float* prelu = (const float*)d_in[8];
  float* out = (float*)d_out;
  char* ws = (char*)d_ws;

  size_t o = 0;
  auto alloc = [&](size_t sz) { size_t r = o; o += (sz + 255) & ~(size_t)255; return r; };
  size_t a_o   = alloc((size_t)kMP * kK * 2);       // 230.6 MB
  size_t wbf_o = alloc((size_t)kC * kK * 2);        // 1.2 MB
  size_t cnt_o = alloc((size_t)kR * kN * 4);        // 1.6 MB
  size_t deg_o = alloc((size_t)kN * 4);
  size_t cs_o  = alloc(256 * 4);
  size_t csq_o = alloc(256 * 4);
  size_t zend  = o;                                 // end of must-zero region
  size_t off_o = alloc((size_t)(kN + 1) * 4);
  size_t cur_o = alloc((size_t)kR * kN * 4);
  size_t eb_o  = alloc((size_t)kE * 2);             // u16 src records
  if (o > ws_size) {
    fprintf(stderr, "[RGCN kernel] ws too small: need %zu have %zu\n", o, ws_size);
    return;
  }

  unsigned short* A    = (unsigned short*)(ws + a_o);
  unsigned short* wbfT = (unsigned short*)(ws + wbf_o);
  int*   cnt  = (int*)(ws + cnt_o);
  int*   deg  = (int*)(ws + deg_o);
  float* cs   = (float*)(ws + cs_o);
  float* csq  = (float*)(ws + csq_o);
  int*   offp = (int*)(ws + off_o);
  int*   cur  = (int*)(ws + cur_o);
  unsigned short* ebuf = (unsigned short*)(ws + eb_o);

  hipMemsetAsync(ws + cnt_o, 0, zend - cnt_o, stream);                       // cnt/deg/cs/csq
  hipMemsetAsync(ws + a_o + (size_t)kN * kK * 2, 0,
                 (size_t)(kMP - kN) * kK * 2, stream);                       // A pad rows
  k_count<<<(kE + 255) / 256, 256, 0, stream>>>(ei, ea, cnt, deg);
  k_convert_x<<<(kN * kC / 4) / 256, 256, 0, stream>>>(x, A);
  k_convert_w<<<(kC * kK + 255) / 256, 256, 0, stream>>>(W, root, wbfT);
  k_scan<<<1, 1024, 0, stream>>>(deg, offp);
  k_grp<<<(kN + 255) / 256, 256, 0, stream>>>(offp, cnt, cur);
  k_fill<<<(kE + 255) / 256, 256, 0, stream>>>(ei, ea, cur, ebuf);
  k_agg<<<(kN + 3) / 4, 256, 0, stream>>>(ebuf, offp, cnt, A);
  k_gemm<<<dim3(kC / 128, kMP / 128), 256, 0, stream>>>(A, wbfT, out, bias, cs, csq);
  k_final<<<(kN * kC / 4) / 256, 256, 0, stream>>>(out, x, cs, csq, bias, gamma, beta, prelu);
}